// Round 17
// baseline (1446.329 us; speedup 1.0000x reference)
//
#include <hip/hip_runtime.h>
#include <hip/hip_bf16.h>

typedef __attribute__((ext_vector_type(8)))  short bf16x8;
typedef __attribute__((ext_vector_type(16))) float f32x16;

constexpr int EMBED = 64;
constexpr int RBF   = 16;
constexpr int SCAN_TILE = 1024;

__device__ __forceinline__ short f2bf(float f) {
    __hip_bfloat16 h = __float2bfloat16(f);   // RNE
    return *reinterpret_cast<short*>(&h);
}
__device__ __forceinline__ float bf2f(short s) {
    unsigned u = ((unsigned)(unsigned short)s) << 16;
    return __uint_as_float(u);
}
__device__ __forceinline__ unsigned pk_bf(float lo, float hi) {
    unsigned l = (unsigned short)f2bf(lo);
    unsigned h = (unsigned short)f2bf(hi);
    return l | (h << 16);
}
__device__ __forceinline__ float silu(float x) {
    return x * __builtin_amdgcn_rcpf(1.0f + __expf(-x));
}

// bf16(pi), bf16(pi/2) (r10-validated angle constants)
constexpr float PI_BF  = 3.140625f;
constexpr float PI2_BF = 1.5703125f;

// C/D row map for 32x32 MFMA (r12-validated)
__device__ __forceinline__ int crow(int j, int h) {
    return (j & 3) + 8 * (j >> 2) + 4 * h;
}

// ======================= CSR construction (validated r13/r15) ==============
__global__ __launch_bounds__(256) void k_hist(
    const int* __restrict__ ei, int* __restrict__ counts, int E)
{
    int i = blockIdx.x * 256 + threadIdx.x;
    if (i < E) atomicAdd(&counts[ei[i]], 1);
}

__global__ __launch_bounds__(256) void k_scan1(
    const int* __restrict__ counts, int* __restrict__ offsets,
    int* __restrict__ bsums, int nn)
{
    __shared__ int lds[256];
    const int t = threadIdx.x;
    const int base = blockIdx.x * SCAN_TILE;
    int v[4]; int s = 0;
#pragma unroll
    for (int j = 0; j < 4; ++j) {
        const int i = base + t * 4 + j;
        v[j] = (i < nn) ? counts[i] : 0;
        s += v[j];
    }
    lds[t] = s;
    __syncthreads();
    for (int off = 1; off < 256; off <<= 1) {
        int x = (t >= off) ? lds[t - off] : 0;
        __syncthreads();
        lds[t] += x;
        __syncthreads();
    }
    int run = lds[t] - s;
    if (t == 255) bsums[blockIdx.x] = lds[255];
#pragma unroll
    for (int j = 0; j < 4; ++j) {
        const int i = base + t * 4 + j;
        if (i < nn) offsets[i] = run;
        run += v[j];
    }
}

__global__ __launch_bounds__(256) void k_scan2(int* __restrict__ bsums, int nblk)
{
    __shared__ int lds[256];
    const int t = threadIdx.x;
    if (nblk <= 256) {
        const int v = (t < nblk) ? bsums[t] : 0;
        lds[t] = v;
        __syncthreads();
        for (int off = 1; off < 256; off <<= 1) {
            int x = (t >= off) ? lds[t - off] : 0;
            __syncthreads();
            lds[t] += x;
            __syncthreads();
        }
        if (t < nblk) bsums[t] = lds[t] - v;
    } else if (t == 0) {
        int a = 0;
        for (int i = 0; i < nblk; ++i) { int tv = bsums[i]; bsums[i] = a; a += tv; }
    }
}

__global__ __launch_bounds__(256) void k_scan3(
    int* __restrict__ offsets, const int* __restrict__ bsums,
    int* __restrict__ counts, int nn, int Etot)
{
    const int base = blockIdx.x * SCAN_TILE;
    const int add = bsums[blockIdx.x];
#pragma unroll
    for (int j = 0; j < 4; ++j) {
        const int i = base + threadIdx.x * 4 + j;
        if (i < nn) { offsets[i] += add; counts[i] = 0; }   // counts -> cursor
    }
    if (blockIdx.x == 0 && threadIdx.x == 0) offsets[nn] = Etot;
}

// slot scatter: eidf = eid | selfloop<<31 ; srow = destination row
__global__ __launch_bounds__(256) void k_scatter2(
    const int* __restrict__ ei, const int* __restrict__ offsets,
    int* __restrict__ cursor, int* __restrict__ eidf,
    int* __restrict__ srow, int E)
{
    int i = blockIdx.x * 256 + threadIdx.x;
    if (i < E) {
        const int row = ei[i];
        const int col = ei[E + i];
        const int p = atomicAdd(&cursor[row], 1);
        const int slot = offsets[row] + p;
        eidf[slot] = i | ((row == col) ? (int)0x80000000 : 0);
        srow[slot] = row;
    }
}

// ======================= edge kernel: sorted gather + LDS aggregation ======
// Block owns 256 consecutive sorted slots; gathers rbf rows (L3-resident),
// r12 GEMM structure, accumulates into LDS agg (node range <= 64 typical),
// flushes touched rows with fp32 global atomics (~30 MB total payload).
template <bool GUARD>
__global__ __launch_bounds__(256, 2) void edge_gather(
    const float* __restrict__ rbf,
    const int* __restrict__ eidf,
    const int* __restrict__ srow,
    const float* __restrict__ W1,
    const float* __restrict__ b1,
    const float* __restrict__ W2,
    const float* __restrict__ b2,
    float* __restrict__ agg,
    int s_base, int E)
{
    __shared__ __align__(16) short lds_msg[4][32 * 64];  // 16 KB
    __shared__ __align__(16) float lds_agg[64][64];      // 16 KB
    __shared__ int lds_eid[256];
    __shared__ int lds_row[256];
    __shared__ int wave_any[4];

    const int tid  = threadIdx.x;
    const int lane = tid & 63;
    const int wave = tid >> 6;
    const int n = lane & 31;
    const int h = lane >> 5;
    const int s0 = s_base + blockIdx.x * 256;

    // ---- stage slots ----
    {
        const int s = s0 + tid;
        int ef = 0, rw = 0;
        if (!GUARD || s < E) { ef = eidf[s]; rw = srow[s]; }
        lds_eid[tid] = ef;
        lds_row[tid] = rw;
        const bool fl = (!GUARD || s < E) && (ef < 0);
        const unsigned long long m = __ballot(fl);
        if (lane == 0) wave_any[wave] = (m != 0ull);
    }
    // ---- zero LDS agg ----
    {
        float4* az = reinterpret_cast<float4*>(&lds_agg[0][0]);
#pragma unroll
        for (int k = 0; k < 4; ++k) az[tid + 256 * k] = float4{0, 0, 0, 0};
    }
    __syncthreads();
    const int rowbase = lds_row[0];

    // ---- B fragments + folded biases (r12-validated) ----
    bf16x8 b1f[2];
    float  b1v[2], dlt[2], b2v[2];
#pragma unroll
    for (int hh = 0; hh < 2; ++hh) {
        const int ch = 2 * n + hh;
#pragma unroll
        for (int j = 0; j < 8; ++j)
            b1f[hh][j] = f2bf(W1[(h * 8 + j) * EMBED + ch]);
        const float w16 = bf2f(f2bf(W1[RBF * EMBED + ch]));
        b1v[hh] = b1[ch] + PI_BF * w16;          // angle==pi folded into bias
        dlt[hh] = (PI2_BF - PI_BF) * w16;        // self-loop correction
        b2v[hh] = b2[ch];
    }
    bf16x8 b2f[4][2];
#pragma unroll
    for (int kk = 0; kk < 4; ++kk)
#pragma unroll
        for (int hh = 0; hh < 2; ++hh) {
            const int ch = 2 * n + hh;
#pragma unroll
            for (int j = 0; j < 8; ++j)
                b2f[kk][hh][j] = f2bf(W2[(kk * 16 + h * 8 + j) * EMBED + ch]);
        }

    char* const sl = reinterpret_cast<char*>(lds_msg[wave]);

    // ---- hoisted A1 gathers (both tiles in flight) ----
    bf16x8 a1[2];
#pragma unroll
    for (int mt = 0; mt < 2; ++mt) {
        bf16x8 a = {};
        const int sl_ = wave * 64 + mt * 32 + n;
        if (!GUARD || (s0 + sl_) < E) {
            const int e = lds_eid[sl_] & 0x7FFFFFFF;
            const float* rp = rbf + (size_t)e * RBF + h * 8;
            const float4 p0 = *reinterpret_cast<const float4*>(rp);
            const float4 p1 = *reinterpret_cast<const float4*>(rp + 4);
            a[0] = f2bf(p0.x); a[1] = f2bf(p0.y); a[2] = f2bf(p0.z); a[3] = f2bf(p0.w);
            a[4] = f2bf(p1.x); a[5] = f2bf(p1.y); a[6] = f2bf(p1.z); a[7] = f2bf(p1.w);
        }
        a1[mt] = a;
    }

#pragma unroll
    for (int mt = 0; mt < 2; ++mt) {
        const int el0 = wave * 64 + mt * 32;
        if (GUARD && (s0 + el0) >= E) break;

        // ---- GEMM1, angle folded into bias ----
        f32x16 accA, accB;
#pragma unroll
        for (int j = 0; j < 16; ++j) { accA[j] = b1v[0]; accB[j] = b1v[1]; }
        accA = __builtin_amdgcn_mfma_f32_32x32x16_bf16(a1[mt], b1f[0], accA, 0, 0, 0);
        accB = __builtin_amdgcn_mfma_f32_32x32x16_bf16(a1[mt], b1f[1], accB, 0, 0, 0);

        if (wave_any[wave]) {
#pragma unroll
            for (int j = 0; j < 16; ++j) {
                const int m = crow(j, h);
                if (lds_eid[el0 + m] < 0) { accA[j] += dlt[0]; accB[j] += dlt[1]; }
            }
        }

        // ---- SiLU + pk-bf16 swizzled LDS write ----
#pragma unroll
        for (int j = 0; j < 16; ++j) {
            const int m = crow(j, h);
            const unsigned u = pk_bf(silu(accA[j]), silu(accB[j]));
            *reinterpret_cast<unsigned*>(sl + m * 128 + ((4 * n) ^ ((m & 7) << 4))) = u;
        }
        __builtin_amdgcn_wave_barrier();

        // ---- GEMM2 ----
        f32x16 acc2A, acc2B;
#pragma unroll
        for (int j = 0; j < 16; ++j) { acc2A[j] = b2v[0]; acc2B[j] = b2v[1]; }
#pragma unroll
        for (int kk = 0; kk < 4; ++kk) {
            const int byte = n * 128 + ((kk * 32 + h * 16) ^ ((n & 7) << 4));
            const bf16x8 a2 = *reinterpret_cast<const bf16x8*>(sl + byte);
            acc2A = __builtin_amdgcn_mfma_f32_32x32x16_bf16(a2, b2f[kk][0], acc2A, 0, 0, 0);
            acc2B = __builtin_amdgcn_mfma_f32_32x32x16_bf16(a2, b2f[kk][1], acc2B, 0, 0, 0);
        }
        __builtin_amdgcn_wave_barrier();

        // ---- LDS aggregation (clustered destinations) ----
#pragma unroll
        for (int j = 0; j < 16; ++j) {
            const int m = crow(j, h);
            const int slotI = el0 + m;
            if (!GUARD || (s0 + slotI) < E) {
                const int lr = lds_row[slotI] - rowbase;
                if (lr < 64) {
                    atomicAdd(&lds_agg[lr][2 * n],     acc2A[j]);
                    atomicAdd(&lds_agg[lr][2 * n + 1], acc2B[j]);
                } else {   // rare overflow: direct global atomics
                    float* const dst = agg + (size_t)lds_row[slotI] * 64u;
                    atomicAdd(dst + 2 * n,     acc2A[j]);
                    atomicAdd(dst + 2 * n + 1, acc2B[j]);
                }
            }
        }
    }
    __syncthreads();

    // ---- flush touched rows (boundary-safe via atomics) ----
    int lastvalid = 255;
    if (GUARD) lastvalid = min(255, E - 1 - s0);
    int rend = lds_row[lastvalid] - rowbase;
    if (rend > 63) rend = 63;
    for (int r = wave; r <= rend; r += 4)
        atomicAdd(&agg[(size_t)(rowbase + r) * 64u + (unsigned)lane], lds_agg[r][lane]);
}

// ======================= node kernel (validated, fp32 agg) =================
__global__ __launch_bounds__(256) void node_kernel_f(
    const float* __restrict__ x, const float* __restrict__ aggv,
    const float* __restrict__ W3, const float* __restrict__ b3,
    const float* __restrict__ W4, const float* __restrict__ b4,
    float* __restrict__ out, int nn)
{
    __shared__ __align__(16) float lds_s[4][EMBED];
    const int lane = threadIdx.x & 63;
    const int wave = threadIdx.x >> 6;
    float w3c[EMBED], w4c[EMBED];
#pragma unroll
    for (int j = 0; j < EMBED; ++j) w3c[j] = W3[j * EMBED + lane];
#pragma unroll
    for (int j = 0; j < EMBED; ++j) w4c[j] = W4[j * EMBED + lane];
    const float b3v = b3[lane];
    const float b4v = b4[lane];
    const float4* s4 = reinterpret_cast<const float4*>(lds_s[wave]);
    const int wid = blockIdx.x * 4 + wave;
    const int nw  = gridDim.x * 4;
    for (int nid = wid; nid < nn; nid += nw) {
        const long long base = (long long)nid * EMBED + lane;
        const float a = aggv[base];
        lds_s[wave][lane] = a;
        __builtin_amdgcn_wave_barrier();
        float acc = b3v;
#pragma unroll
        for (int j4 = 0; j4 < EMBED / 4; ++j4) {
            const float4 sv = s4[j4];
            acc = fmaf(sv.x, w3c[4 * j4 + 0], acc);
            acc = fmaf(sv.y, w3c[4 * j4 + 1], acc);
            acc = fmaf(sv.z, w3c[4 * j4 + 2], acc);
            acc = fmaf(sv.w, w3c[4 * j4 + 3], acc);
        }
        const float s = acc * __builtin_amdgcn_rcpf(1.0f + __expf(-acc));
        __builtin_amdgcn_wave_barrier();
        lds_s[wave][lane] = s;
        __builtin_amdgcn_wave_barrier();
        float acc2 = b4v;
#pragma unroll
        for (int j4 = 0; j4 < EMBED / 4; ++j4) {
            const float4 sv = s4[j4];
            acc2 = fmaf(sv.x, w4c[4 * j4 + 0], acc2);
            acc2 = fmaf(sv.y, w4c[4 * j4 + 1], acc2);
            acc2 = fmaf(sv.z, w4c[4 * j4 + 2], acc2);
            acc2 = fmaf(sv.w, w4c[4 * j4 + 3], acc2);
        }
        __builtin_amdgcn_wave_barrier();
        out[base] = x[base] + acc2;
    }
}

// ======================= fallback: r12 fp32 atomic edge (validated) ========
template <bool GUARD>
__global__ __launch_bounds__(256, 2) void edge_kernel32_fb(
    const float* __restrict__ rbf, const int* __restrict__ ei,
    const float* __restrict__ W1, const float* __restrict__ b1,
    const float* __restrict__ W2, const float* __restrict__ b2,
    float* __restrict__ aggf, int e_base, int E)
{
    __shared__ __align__(16) short lds_s[4][32 * 64];
    __shared__ int lds_row[256];
    __shared__ unsigned char lds_flag[256];
    __shared__ int wave_any[4];
    const int tid = threadIdx.x, lane = tid & 63, wave = tid >> 6;
    const int n = lane & 31, h = lane >> 5;
    const int blk_e0 = e_base + blockIdx.x * 256;
    {
        const int e = blk_e0 + tid;
        const bool v = !GUARD || (e < E);
        const int row = v ? ei[e] : 0;
        const int col = v ? ei[E + e] : 1;
        lds_row[tid] = row;
        const bool fl = v && (row == col);
        lds_flag[tid] = fl;
        const unsigned long long m = __ballot(fl);
        if (lane == 0) wave_any[wave] = (m != 0ull);
    }
    __syncthreads();
    bf16x8 b1f[2];
    float b1v[2], dlt[2], b2v[2];
#pragma unroll
    for (int hh = 0; hh < 2; ++hh) {
        const int ch = 2 * n + hh;
#pragma unroll
        for (int j = 0; j < 8; ++j)
            b1f[hh][j] = f2bf(W1[(h * 8 + j) * EMBED + ch]);
        const float w16 = bf2f(f2bf(W1[RBF * EMBED + ch]));
        b1v[hh] = b1[ch] + PI_BF * w16;
        dlt[hh] = (PI2_BF - PI_BF) * w16;
        b2v[hh] = b2[ch];
    }
    bf16x8 b2f[4][2];
#pragma unroll
    for (int kk = 0; kk < 4; ++kk)
#pragma unroll
        for (int hh = 0; hh < 2; ++hh) {
            const int ch = 2 * n + hh;
#pragma unroll
            for (int j = 0; j < 8; ++j)
                b2f[kk][hh][j] = f2bf(W2[(kk * 16 + h * 8 + j) * EMBED + ch]);
        }
    char* const sl = reinterpret_cast<char*>(lds_s[wave]);
#pragma unroll 1
    for (int mt = 0; mt < 2; ++mt) {
        const int e0 = blk_e0 + wave * 64 + mt * 32;
        if (GUARD && e0 >= E) break;
        const int el0 = wave * 64 + mt * 32;
        bf16x8 a1 = {};
        {
            const int ea = e0 + n;
            if (!GUARD || ea < E) {
                const float4 p0 = *reinterpret_cast<const float4*>(rbf + (long long)ea * RBF + h * 8);
                const float4 p1 = *reinterpret_cast<const float4*>(rbf + (long long)ea * RBF + h * 8 + 4);
                a1[0] = f2bf(p0.x); a1[1] = f2bf(p0.y); a1[2] = f2bf(p0.z); a1[3] = f2bf(p0.w);
                a1[4] = f2bf(p1.x); a1[5] = f2bf(p1.y); a1[6] = f2bf(p1.z); a1[7] = f2bf(p1.w);
            }
        }
        f32x16 accA, accB;
#pragma unroll
        for (int j = 0; j < 16; ++j) { accA[j] = b1v[0]; accB[j] = b1v[1]; }
        accA = __builtin_amdgcn_mfma_f32_32x32x16_bf16(a1, b1f[0], accA, 0, 0, 0);
        accB = __builtin_amdgcn_mfma_f32_32x32x16_bf16(a1, b1f[1], accB, 0, 0, 0);
        if (wave_any[wave]) {
#pragma unroll
            for (int j = 0; j < 16; ++j) {
                const int m = crow(j, h);
                if (lds_flag[el0 + m]) { accA[j] += dlt[0]; accB[j] += dlt[1]; }
            }
        }
#pragma unroll
        for (int j = 0; j < 16; ++j) {
            const int m = crow(j, h);
            const unsigned u = pk_bf(silu(accA[j]), silu(accB[j]));
            *reinterpret_cast<unsigned*>(sl + m * 128 + ((4 * n) ^ ((m & 7) << 4))) = u;
        }
        __builtin_amdgcn_wave_barrier();
        f32x16 acc2A, acc2B;
#pragma unroll
        for (int j = 0; j < 16; ++j) { acc2A[j] = b2v[0]; acc2B[j] = b2v[1]; }
#pragma unroll
        for (int kk = 0; kk < 4; ++kk) {
            const int byte = n * 128 + ((kk * 32 + h * 16) ^ ((n & 7) << 4));
            const bf16x8 a2 = *reinterpret_cast<const bf16x8*>(sl + byte);
            acc2A = __builtin_amdgcn_mfma_f32_32x32x16_bf16(a2, b2f[kk][0], acc2A, 0, 0, 0);
            acc2B = __builtin_amdgcn_mfma_f32_32x32x16_bf16(a2, b2f[kk][1], acc2B, 0, 0, 0);
        }
        __builtin_amdgcn_wave_barrier();
#pragma unroll
        for (int j = 0; j < 16; ++j) {
            const int m = crow(j, h);
            const int eat = e0 + m;
            if (!GUARD || eat < E) {
                float* const dst = aggf + (size_t)lds_row[el0 + m] * 64u;
                atomicAdd(dst + 2 * n,     acc2A[j]);
                atomicAdd(dst + 2 * n + 1, acc2B[j]);
            }
        }
    }
}

// ===========================================================================
extern "C" void kernel_launch(void* const* d_in, const int* in_sizes, int n_in,
                              void* d_out, int out_size, void* d_ws, size_t ws_size,
                              hipStream_t stream) {
    const float* x      = (const float*)d_in[0];
    const float* rbf    = (const float*)d_in[2];
    const int*   ei     = (const int*)d_in[3];
    const float* W1 = (const float*)d_in[4];
    const float* b1 = (const float*)d_in[5];
    const float* W2 = (const float*)d_in[6];
    const float* b2 = (const float*)d_in[7];
    const float* W3 = (const float*)d_in[8];
    const float* b3 = (const float*)d_in[9];
    const float* W4 = (const float*)d_in[10];
    const float* b4 = (const float*)d_in[11];
    float* out = (float*)d_out;

    const int E  = (int)(in_sizes[3] / 2);
    const int nn = in_sizes[0] / EMBED;
    const int nscan = (nn + SCAN_TILE - 1) / SCAN_TILE;
    const int nsPad = (nscan + 63) & ~63;

    // ws layout: eidf int[E] | srow int[E] | agg f32[nn*64] | offsets | counts | bsums
    int* eidf    = (int*)d_ws;
    int* srow    = eidf + E;
    float* agg   = (float*)(srow + E);
    int* offsets = (int*)(agg + (size_t)nn * EMBED);
    int* counts  = offsets + nn + 1;
    int* bsums   = counts + nn;
    const size_t needed = sizeof(int) * ((size_t)E * 2 + (nn + 1) + nn + nsPad)
                        + sizeof(float) * (size_t)nn * EMBED;

    const int nfull = E / 256;
    const int rem   = E - nfull * 256;
    const unsigned egrid = (unsigned)((E + 255) / 256);

    if (ws_size >= needed) {
        // ---- CSR slots ----
        hipMemsetAsync(counts, 0, sizeof(int) * nn, stream);
        k_hist<<<dim3(egrid), dim3(256), 0, stream>>>(ei, counts, E);
        k_scan1<<<dim3((unsigned)nscan), dim3(256), 0, stream>>>(counts, offsets, bsums, nn);
        k_scan2<<<dim3(1), dim3(256), 0, stream>>>(bsums, nscan);
        k_scan3<<<dim3((unsigned)nscan), dim3(256), 0, stream>>>(offsets, bsums, counts, nn, E);
        k_scatter2<<<dim3(egrid), dim3(256), 0, stream>>>(ei, offsets, counts, eidf, srow, E);
        // ---- agg zero + sorted-gather edge phase ----
        hipMemsetAsync(agg, 0, sizeof(float) * (size_t)nn * EMBED, stream);
        if (nfull)
            edge_gather<false><<<dim3(nfull), dim3(256), 0, stream>>>(
                rbf, eidf, srow, W1, b1, W2, b2, agg, 0, E);
        if (rem)
            edge_gather<true><<<dim3(1), dim3(256), 0, stream>>>(
                rbf, eidf, srow, W1, b1, W2, b2, agg, nfull * 256, E);
        // ---- node MLP ----
        node_kernel_f<<<dim3(2048), dim3(256), 0, stream>>>(
            x, agg, W3, b3, W4, b4, out, nn);
    } else {
        // fallback: r12-structure fp32 atomics into d_out, node MLP in place
        hipMemsetAsync(out, 0, (size_t)nn * EMBED * sizeof(float), stream);
        if (nfull)
            edge_kernel32_fb<false><<<dim3(nfull), dim3(256), 0, stream>>>(
                rbf, ei, W1, b1, W2, b2, out, 0, E);
        if (rem)
            edge_kernel32_fb<true><<<dim3(1), dim3(256), 0, stream>>>(
                rbf, ei, W1, b1, W2, b2, out, nfull * 256, E);
        node_kernel_f<<<dim3(2048), dim3(256), 0, stream>>>(
            x, out, W3, b3, W4, b4, out, nn);
    }
}

// Round 18
// 393.680 us; speedup vs baseline: 3.6739x; 3.6739x over previous
//
#include <hip/hip_runtime.h>
#include <hip/hip_fp16.h>
#include <hip/hip_bf16.h>

typedef __attribute__((ext_vector_type(8)))  short bf16x8;
typedef __attribute__((ext_vector_type(4)))  float f32x4;
typedef __attribute__((ext_vector_type(16))) float f32x16;

constexpr int EMBED = 64;
constexpr int RBF   = 16;

__device__ __forceinline__ short f2bf(float f) {
    __hip_bfloat16 h = __float2bfloat16(f);   // RNE
    return *reinterpret_cast<short*>(&h);
}
__device__ __forceinline__ float bf2f(short s) {
    unsigned u = ((unsigned)(unsigned short)s) << 16;
    return __uint_as_float(u);
}
__device__ __forceinline__ unsigned pk_bf(float lo, float hi) {
    unsigned l = (unsigned short)f2bf(lo);
    unsigned h = (unsigned short)f2bf(hi);
    return l | (h << 16);
}
__device__ __forceinline__ unsigned pk_f16(float lo, float hi) {
    __half2 h = __halves2half2(__float2half_rn(lo), __float2half_rn(hi));
    return *reinterpret_cast<unsigned*>(&h);
}
__device__ __forceinline__ void atom_pk_add_f16(__half* addr, unsigned data) {
    asm volatile("global_atomic_pk_add_f16 %0, %1, off"
                 :: "v"(addr), "v"(data) : "memory");
}
__device__ __forceinline__ float silu(float x) {
    return x * __builtin_amdgcn_rcpf(1.0f + __expf(-x));
}

// bf16(pi), bf16(pi/2) as floats (r10-validated angle constants)
constexpr float PI_BF  = 3.140625f;
constexpr float PI2_BF = 1.5703125f;

// C/D row map for 32x32 MFMA: row = (reg&3) + 8*(reg>>2) + 4*(lane>>5)
__device__ __forceinline__ int crow(int j, int h) {
    return (j & 3) + 8 * (j >> 2) + 4 * h;
}

// ======================= edge kernel, 32x32x16 MFMA ========================
// GEMM1: rbf @ W1[0:16] (K=16), angle folded into bias (+ rare self-loop fix).
// Channel-interleave: accA = channels 2n, accB = channels 2n+1 (n=lane&31)
// -> pk pairs are lane-local for LDS writes and atomics.
template <bool GUARD, bool F16>
__global__ __launch_bounds__(256, 2) void edge_kernel32(
    const float* __restrict__ rbf,
    const int* __restrict__ ei,
    const float* __restrict__ W1,
    const float* __restrict__ b1,
    const float* __restrict__ W2,
    const float* __restrict__ b2,
    void* __restrict__ agg,
    int e_base, int E)
{
    __shared__ __align__(16) short lds_s[4][32 * 64];  // 16 KB: per-wave 32e x 64ch
    __shared__ int lds_row[256];
    __shared__ unsigned char lds_flag[256];
    __shared__ int wave_any[4];

    const int tid  = threadIdx.x;
    const int lane = tid & 63;
    const int wave = tid >> 6;
    const int n = lane & 31;     // channel-pair index / edge index (m)
    const int h = lane >> 5;     // k-half
    const int blk_e0 = e_base + blockIdx.x * 256;

    // ---- stage rows + self-loop flags (coalesced) ----
    {
        const int e = blk_e0 + tid;
        const bool v = !GUARD || (e < E);
        const int row = v ? ei[e] : 0;
        const int col = v ? ei[E + e] : 1;
        lds_row[tid]  = row;
        const bool fl = v && (row == col);
        lds_flag[tid] = fl;
        const unsigned long long m = __ballot(fl);
        if (lane == 0) wave_any[wave] = (m != 0ull);
    }
    __syncthreads();

    // ---- B fragments + folded biases (VGPR-resident) ----
    // B layout (32x32x16): nB = lane&31 -> channel 2n+hh ; k = h*8 + j
    bf16x8 b1f[2];
    float  b1v[2], dlt[2], b2v[2];
#pragma unroll
    for (int hh = 0; hh < 2; ++hh) {
        const int ch = 2 * n + hh;
#pragma unroll
        for (int j = 0; j < 8; ++j)
            b1f[hh][j] = f2bf(W1[(h * 8 + j) * EMBED + ch]);
        const float w16 = bf2f(f2bf(W1[RBF * EMBED + ch]));
        b1v[hh] = b1[ch] + PI_BF * w16;          // angle==pi folded into bias
        dlt[hh] = (PI2_BF - PI_BF) * w16;        // self-loop correction
        b2v[hh] = b2[ch];
    }
    bf16x8 b2f[4][2];                            // [k-step][channel half]
#pragma unroll
    for (int kk = 0; kk < 4; ++kk)
#pragma unroll
        for (int hh = 0; hh < 2; ++hh) {
            const int ch = 2 * n + hh;
#pragma unroll
            for (int j = 0; j < 8; ++j)
                b2f[kk][hh][j] = f2bf(W2[(kk * 16 + h * 8 + j) * EMBED + ch]);
        }

    char* const sl = reinterpret_cast<char*>(lds_s[wave]);

#pragma unroll 1
    for (int mt = 0; mt < 2; ++mt) {
        const int e0  = blk_e0 + wave * 64 + mt * 32;
        if (GUARD && e0 >= E) break;
        const int el0 = wave * 64 + mt * 32;

        // ---- A1: edge m=n, k = h*8+j -> rbf[e0+n][h*8 .. h*8+8) ----
        bf16x8 a1 = {};
        {
            const int ea = e0 + n;
            if (!GUARD || ea < E) {
                const float4 p0 = *reinterpret_cast<const float4*>(rbf + (long long)ea * RBF + h * 8);
                const float4 p1 = *reinterpret_cast<const float4*>(rbf + (long long)ea * RBF + h * 8 + 4);
                a1[0] = f2bf(p0.x); a1[1] = f2bf(p0.y); a1[2] = f2bf(p0.z); a1[3] = f2bf(p0.w);
                a1[4] = f2bf(p1.x); a1[5] = f2bf(p1.y); a1[6] = f2bf(p1.z); a1[7] = f2bf(p1.w);
            }
        }

        // ---- GEMM1 (one MFMA per channel half), bias-initialized ----
        f32x16 accA, accB;
#pragma unroll
        for (int j = 0; j < 16; ++j) { accA[j] = b1v[0]; accB[j] = b1v[1]; }
        accA = __builtin_amdgcn_mfma_f32_32x32x16_bf16(a1, b1f[0], accA, 0, 0, 0);
        accB = __builtin_amdgcn_mfma_f32_32x32x16_bf16(a1, b1f[1], accB, 0, 0, 0);

        // ---- rare self-loop correction ----
        if (wave_any[wave]) {
#pragma unroll
            for (int j = 0; j < 16; ++j) {
                const int m = crow(j, h);
                if (lds_flag[el0 + m]) { accA[j] += dlt[0]; accB[j] += dlt[1]; }
            }
        }

        // ---- SiLU + pk-bf16 swizzled LDS write ----
        // edge m = crow(j,h), channel-pair byte 4n ; swz = (m&7)<<4
#pragma unroll
        for (int j = 0; j < 16; ++j) {
            const int m = crow(j, h);
            const unsigned u = pk_bf(silu(accA[j]), silu(accB[j]));
            *reinterpret_cast<unsigned*>(sl + m * 128 + ((4 * n) ^ ((m & 7) << 4))) = u;
        }
        __builtin_amdgcn_wave_barrier();

        // ---- GEMM2: A2 streamed from LDS (shared by both halves) ----
        f32x16 acc2A, acc2B;
#pragma unroll
        for (int j = 0; j < 16; ++j) { acc2A[j] = b2v[0]; acc2B[j] = b2v[1]; }
#pragma unroll
        for (int kk = 0; kk < 4; ++kk) {
            // lane's edge m=n, channels [kk*16 + h*8, +8) -> bytes kk*32+h*16
            const int byte = n * 128 + ((kk * 32 + h * 16) ^ ((n & 7) << 4));
            const bf16x8 a2 = *reinterpret_cast<const bf16x8*>(sl + byte);
            acc2A = __builtin_amdgcn_mfma_f32_32x32x16_bf16(a2, b2f[kk][0], acc2A, 0, 0, 0);
            acc2B = __builtin_amdgcn_mfma_f32_32x32x16_bf16(a2, b2f[kk][1], acc2B, 0, 0, 0);
        }
        __builtin_amdgcn_wave_barrier();   // WAR vs next tile's writes

        // ---- scatter: slot j -> edge crow(j,h); 32 lanes/half cover the
        //      edge's full 128-B row with consecutive pk atomics ----
#pragma unroll
        for (int j = 0; j < 16; ++j) {
            const int m = crow(j, h);
            const int eat = e0 + m;
            if (!GUARD || eat < E) {
                const unsigned row = (unsigned)lds_row[el0 + m];
                if (F16) {
                    __half* const dst = reinterpret_cast<__half*>(agg) + row * 64u;
                    atom_pk_add_f16(dst + 2 * n, pk_f16(acc2A[j], acc2B[j]));
                } else {
                    float* const dst = reinterpret_cast<float*>(agg) + row * 64u;
                    atomicAdd(dst + 2 * n,     acc2A[j]);
                    atomicAdd(dst + 2 * n + 1, acc2B[j]);
                }
            }
        }
    }
}

// ======================= node kernel (r5/r10-validated) ====================
template <bool F16>
__global__ __launch_bounds__(256) void node_kernel(
    const float* __restrict__ x, const void* __restrict__ aggv,
    const float* __restrict__ W3, const float* __restrict__ b3,
    const float* __restrict__ W4, const float* __restrict__ b4,
    float* __restrict__ out, int nn)
{
    __shared__ __align__(16) float lds_s[4][EMBED];
    const int lane = threadIdx.x & 63;
    const int wave = threadIdx.x >> 6;
    float w3c[EMBED], w4c[EMBED];
#pragma unroll
    for (int j = 0; j < EMBED; ++j) w3c[j] = W3[j * EMBED + lane];
#pragma unroll
    for (int j = 0; j < EMBED; ++j) w4c[j] = W4[j * EMBED + lane];
    const float b3v = b3[lane];
    const float b4v = b4[lane];
    const float4* s4 = reinterpret_cast<const float4*>(lds_s[wave]);
    const int wid = blockIdx.x * 4 + wave;
    const int nw  = gridDim.x * 4;
    for (int n = wid; n < nn; n += nw) {
        const long long base = (long long)n * EMBED + lane;
        float a;
        if (F16) a = __half2float(reinterpret_cast<const __half*>(aggv)[base]);
        else     a = reinterpret_cast<const float*>(aggv)[base];
        lds_s[wave][lane] = a;
        __builtin_amdgcn_wave_barrier();
        float acc = b3v;
#pragma unroll
        for (int j4 = 0; j4 < EMBED / 4; ++j4) {
            const float4 sv = s4[j4];
            acc = fmaf(sv.x, w3c[4 * j4 + 0], acc);
            acc = fmaf(sv.y, w3c[4 * j4 + 1], acc);
            acc = fmaf(sv.z, w3c[4 * j4 + 2], acc);
            acc = fmaf(sv.w, w3c[4 * j4 + 3], acc);
        }
        const float s = acc * __builtin_amdgcn_rcpf(1.0f + __expf(-acc));
        __builtin_amdgcn_wave_barrier();
        lds_s[wave][lane] = s;
        __builtin_amdgcn_wave_barrier();
        float acc2 = b4v;
#pragma unroll
        for (int j4 = 0; j4 < EMBED / 4; ++j4) {
            const float4 sv = s4[j4];
            acc2 = fmaf(sv.x, w4c[4 * j4 + 0], acc2);
            acc2 = fmaf(sv.y, w4c[4 * j4 + 1], acc2);
            acc2 = fmaf(sv.z, w4c[4 * j4 + 2], acc2);
            acc2 = fmaf(sv.w, w4c[4 * j4 + 3], acc2);
        }
        __builtin_amdgcn_wave_barrier();
        out[base] = x[base] + acc2;
    }
}

// ===========================================================================
extern "C" void kernel_launch(void* const* d_in, const int* in_sizes, int n_in,
                              void* d_out, int out_size, void* d_ws, size_t ws_size,
                              hipStream_t stream) {
    const float* x      = (const float*)d_in[0];
    const float* rbf    = (const float*)d_in[2];
    const int*   ei     = (const int*)d_in[3];
    const float* W1 = (const float*)d_in[4];
    const float* b1 = (const float*)d_in[5];
    const float* W2 = (const float*)d_in[6];
    const float* b2 = (const float*)d_in[7];
    const float* W3 = (const float*)d_in[8];
    const float* b3 = (const float*)d_in[9];
    const float* W4 = (const float*)d_in[10];
    const float* b4 = (const float*)d_in[11];
    float* out = (float*)d_out;

    const int E  = (int)(in_sizes[3] / 2);
    const int nn = in_sizes[0] / EMBED;

    void* agg16 = d_ws;
    const size_t neededF16 = (size_t)nn * EMBED * sizeof(__half);

    const int nfull = E / 256;
    const int rem   = E - nfull * 256;

    if (ws_size >= neededF16) {
        hipMemsetAsync(agg16, 0, neededF16, stream);
        if (nfull)
            edge_kernel32<false, true><<<dim3(nfull), dim3(256), 0, stream>>>(
                rbf, ei, W1, b1, W2, b2, agg16, 0, E);
        if (rem)
            edge_kernel32<true, true><<<dim3(1), dim3(256), 0, stream>>>(
                rbf, ei, W1, b1, W2, b2, agg16, nfull * 256, E);
        node_kernel<true><<<dim3(2048), dim3(256), 0, stream>>>(
            x, agg16, W3, b3, W4, b4, out, nn);
    } else {
        // fallback: fp32 atomics into d_out, node MLP in place
        hipMemsetAsync(out, 0, (size_t)nn * EMBED * sizeof(float), stream);
        if (nfull)
            edge_kernel32<false, false><<<dim3(nfull), dim3(256), 0, stream>>>(
                rbf, ei, W1, b1, W2, b2, out, 0, E);
        if (rem)
            edge_kernel32<true, false><<<dim3(1), dim3(256), 0, stream>>>(
                rbf, ei, W1, b1, W2, b2, out, nfull * 256, E);
        node_kernel<false><<<dim3(2048), dim3(256), 0, stream>>>(
            x, out, W3, b3, W4, b4, out, nn);
    }
}